// Round 6
// baseline (102.576 us; speedup 1.0000x reference)
//
#include <hip/hip_runtime.h>

// CARAFE: features [4,256,64,64] f32, masks [4,25,128,128] f32 -> out [4,256,128,128] f32
// out[n,c,2h+p,2w+q] = sum_{i,j} masks[n,i*5+j,2h+p,2w+q] * feat[n,c,h+i-2,w+j-2]
//
// Thread owns 1 output row x 4 consecutive cols x 8 channels:
//   - output stores are PLAIN f32x4 (16 B/lane, 128 B contiguous per 8 lanes) --
//     nontemporal f32x2 stores measured at only ~1.55 TB/s drain (the 40 us
//     invariant); plain stores stream at 6.2 TB/s (fill-kernel evidence).
//   - masks: one f32x4 global load per tap (25 total), 8-deep prefetch queue.
//   - features staged once per block in LDS as channel-pair float2 planes;
//     per tap 4x adjacent float2 reads (ds_read2_b64-fusable), 8 FMAs each.

#define CN 4
#define CC 256
#define CH 64
#define CW 64
#define CK 5
#define OH 128
#define OW 128

typedef float f32x4 __attribute__((ext_vector_type(4)));

constexpr int TILE  = 16;             // 16x16 low-res positions per block (32x32 out)
constexpr int SROWS = TILE + 4;       // 20 staged rows
constexpr int LSTR  = 24;             // row stride in float2 units
constexpr int LBUF  = SROWS * LSTR;   // 480 float2 per channel-pair plane
constexpr int CPB   = 8;              // channels per block
constexpr int PPS   = CPB / 2;        // 4 pair planes
constexpr int NTAP  = CK * CK;        // 25
constexpr int MQ    = 8;              // mask prefetch depth (taps)

__global__ __launch_bounds__(256, 4)
void carafe_kernel(const float* __restrict__ feat,
                   const float* __restrict__ masks,
                   float* __restrict__ out)
{
    __shared__ float2 lds[PPS * LBUF];   // 15360 B

    const int tid  = threadIdx.x;
    const int row  = tid >> 3;           // 0..31: output row within tile
    const int colq = tid & 7;            // 0..7: 4 output cols each

    const int w0 = blockIdx.x * TILE;
    const int h0 = blockIdx.y * TILE;
    const int z  = blockIdx.z;           // n*32 + chunk
    const int n  = z >> 5;
    const int c0 = (z & 31) * CPB;

    const int oh = 2 * h0 + row;
    const int ow = 2 * w0 + 4 * colq;    // multiple of 4 -> 16B-aligned

    // ---- mask queue: first MQ taps issued before staging (overlap) ----
    const float* mp = masks + (((size_t)n * NTAP) * OH + oh) * OW + ow;
    f32x4 q[MQ];
#pragma unroll
    for (int t = 0; t < MQ; ++t)
        q[t] = *(const f32x4*)(mp + (size_t)t * (OH * OW));

    // ---- feature staging: thread t<200 owns float2-pair (row r, cols qq,qq+1) ----
    const int r  = tid / 10;
    const int qq = 2 * (tid % 10);
    const int gr = h0 - 2 + r;
    const int gc = w0 - 2 + qq;          // even -> float2-aligned
    const bool sv = (tid < 200) & (gr >= 0) & (gr < CH) & (gc >= 0) & (gc <= CW - 2);
    const int goff = sv ? (gr * CW + gc) : 0;
    const int l    = r * LSTR + qq;      // even -> 16B-aligned LDS slot

    const float* fbase = feat + (size_t)(n * CC + c0) * (CH * CW);

    float2 pa[PPS], pb[PPS];
#pragma unroll
    for (int p = 0; p < PPS; ++p) {
        const float* f0 = fbase + (size_t)(2 * p) * (CH * CW);
        pa[p] = sv ? *(const float2*)(f0 + goff) : make_float2(0.f, 0.f);
        pb[p] = sv ? *(const float2*)(f0 + CH * CW + goff) : make_float2(0.f, 0.f);
    }
    if (tid < 200) {
#pragma unroll
        for (int p = 0; p < PPS; ++p)
            *(f32x4*)&lds[p * LBUF + l] = (f32x4){pa[p].x, pb[p].x, pa[p].y, pb[p].y};
    }

    __syncthreads();

    // ---- accumulators: 4 out pixels (one row) x 8 channels ----
    f32x4 acc[CPB];
#pragma unroll
    for (int c = 0; c < CPB; ++c) acc[c] = (f32x4){0.f, 0.f, 0.f, 0.f};

    // low-res row (row>>1); out cols {4colq..4colq+3} -> low-res cols 2colq+{0,1} (+halo)
    const float2* lbb = &lds[(row >> 1) * LSTR + 2 * colq];

#pragma unroll
    for (int t = 0; t < NTAP; ++t) {
        const int i = t / CK, j = t % CK;
        const int slot = t % MQ;                 // static after full unroll
        const f32x4 m = q[slot];

        if (t + MQ < NTAP)                       // refill 8 taps (~600 cyc) ahead
            q[slot] = *(const f32x4*)(mp + (size_t)(t + MQ) * (OH * OW));

#pragma unroll
        for (int p = 0; p < PPS; ++p) {
            const float2 fA = lbb[p * LBUF + i * LSTR + j];       // wpos0: ch 2p,2p+1
            const float2 fB = lbb[p * LBUF + i * LSTR + j + 1];   // wpos1
            acc[2 * p][0]     += m[0] * fA.x;  acc[2 * p][1]     += m[1] * fA.x;
            acc[2 * p][2]     += m[2] * fB.x;  acc[2 * p][3]     += m[3] * fB.x;
            acc[2 * p + 1][0] += m[0] * fA.y;  acc[2 * p + 1][1] += m[1] * fA.y;
            acc[2 * p + 1][2] += m[2] * fB.y;  acc[2 * p + 1][3] += m[3] * fB.y;
        }
    }

    // ---- epilogue: plain coalesced f32x4 stores (1 KiB per wave-inst) ----
    float* obase = out + (((size_t)(n * CC + c0) * OH + oh) * OW + ow);
#pragma unroll
    for (int c = 0; c < CPB; ++c)
        *(f32x4*)(obase + (size_t)c * (OH * OW)) = acc[c];
}

extern "C" void kernel_launch(void* const* d_in, const int* in_sizes, int n_in,
                              void* d_out, int out_size, void* d_ws, size_t ws_size,
                              hipStream_t stream) {
    const float* feat  = (const float*)d_in[0];
    const float* masks = (const float*)d_in[1];
    float* out = (float*)d_out;

    dim3 grid(CW / TILE, CH / TILE, CN * (CC / CPB));  // 4 x 4 x 128 = 2048 blocks
    dim3 block(256);
    hipLaunchKernelGGL(carafe_kernel, grid, block, 0, stream, feat, masks, out);
}

// Round 7
// 99.726 us; speedup vs baseline: 1.0286x; 1.0286x over previous
//
#include <hip/hip_runtime.h>

// CARAFE: features [4,256,64,64] f32, masks [4,25,128,128] f32 -> out [4,256,128,128] f32
// out[n,c,2h+p,2w+q] = sum_{i,j} masks[n,i*5+j,2h+p,2w+q] * feat[n,c,h+i-2,w+j-2]
//
// Fabric-traffic-minimizing structure: mask tile per block is 102.4 KB no matter
// how many channels the block covers, so channels/block (CPB) directly divides
// total mask re-read volume. CPB=32 -> 512 blocks -> 52 MB mask reads (was 210).
// The 100 mask floats live in VGPRs for the whole block, pinned by an opaque
// asm fence so the compiler cannot rematerialize the global loads (R3's VGPR=72
// proved it does exactly that without the fence). Channels run in 4 phases of 8
// with double-buffered LDS feature staging and the verified quad-mapped FMA core.

#define CN 4
#define CC 256
#define CH 64
#define CW 64
#define CK 5
#define OH 128
#define OW 128

typedef float f32x2 __attribute__((ext_vector_type(2)));
typedef float f32x4 __attribute__((ext_vector_type(4)));

constexpr int TILE  = 16;             // 16x16 low-res positions per block
constexpr int SROWS = TILE + 4;       // 20 staged rows
constexpr int LSTR  = 24;             // row stride in float2 units
constexpr int LBUF  = SROWS * LSTR;   // 480 float2 per channel-pair plane
constexpr int GPC   = 8;              // channels per phase
constexpr int PPS   = GPC / 2;        // 4 pair planes per phase
constexpr int NPH   = 4;              // phases
constexpr int CPB   = GPC * NPH;      // 32 channels per block
constexpr int NTAP  = CK * CK;        // 25

__global__ __launch_bounds__(256, 2)
void carafe_kernel(const float* __restrict__ feat,
                   const float* __restrict__ masks,
                   float* __restrict__ out)
{
    __shared__ float2 lds[2 * PPS * LBUF];   // double buffer, 30720 B

    const int tid  = threadIdx.x;
    const int wloc = tid & 15;
    const int hloc = tid >> 4;

    const int w0 = blockIdx.x * TILE;
    const int h0 = blockIdx.y * TILE;
    const int z  = blockIdx.z;           // n*8 + chunk
    const int n  = z >> 3;
    const int c0 = (z & 7) * CPB;

    // ---- masks: quad mapping, 100 floats -> VGPRs, loaded ONCE per block ----
    const int oh0 = 2 * (h0 + hloc);
    const int ow0 = 2 * (w0 + wloc);
    const float* mp = masks + (((size_t)n * NTAP) * OH + oh0) * OW + ow0;

    float2 m0[NTAP], m1[NTAP];
#pragma unroll
    for (int t = 0; t < NTAP; ++t) {
        m0[t] = *(const float2*)(mp + (size_t)t * (OH * OW));
        m1[t] = *(const float2*)(mp + (size_t)t * (OH * OW) + OW);
    }

    // ---- feature staging setup: thread t<200 owns (row r, cols qq,qq+1) ----
    const int r  = tid / 10;
    const int qq = 2 * (tid % 10);
    const int gr = h0 - 2 + r;
    const int gc = w0 - 2 + qq;          // even -> float2-aligned
    const bool sv = (tid < 200) & (gr >= 0) & (gr < CH) & (gc >= 0) & (gc <= CW - 2);
    const int goff = sv ? (gr * CW + gc) : 0;
    const int l    = r * LSTR + qq;      // even -> 16B-aligned LDS slot

    const float* fbase = feat + (size_t)(n * CC + c0) * (CH * CW);

    float2 pa[PPS], pb[PPS];
    auto loadPhase = [&](int ph) {
#pragma unroll
        for (int p = 0; p < PPS; ++p) {
            const float* f0 = fbase + (size_t)(ph * GPC + 2 * p) * (CH * CW);
            pa[p] = sv ? *(const float2*)(f0 + goff) : make_float2(0.f, 0.f);
            pb[p] = sv ? *(const float2*)(f0 + CH * CW + goff) : make_float2(0.f, 0.f);
        }
    };
    auto writePhase = [&](int buf) {
        if (tid < 200) {
            float2* dst = &lds[buf * (PPS * LBUF)];
#pragma unroll
            for (int p = 0; p < PPS; ++p)
                *(f32x4*)&dst[p * LBUF + l] = (f32x4){pa[p].x, pb[p].x, pa[p].y, pb[p].y};
        }
    };

    loadPhase(0);

    // Opaque fence: pins the 100 mask values into VGPRs; compiler cannot
    // rematerialize the loads (it can't see through the asm).
#pragma unroll
    for (int t = 0; t < NTAP; ++t)
        asm volatile("" : "+v"(m0[t].x), "+v"(m0[t].y), "+v"(m1[t].x), "+v"(m1[t].y));

    writePhase(0);
    loadPhase(1);

    float* obase = out + (((size_t)(n * CC + c0) * OH + oh0) * OW + ow0);

    for (int ph = 0; ph < NPH; ++ph) {
        __syncthreads();                         // buf[ph&1] ready

        if (ph + 1 < NPH) writePhase((ph + 1) & 1);
        if (ph + 2 < NPH) loadPhase(ph + 2);

        const float2* lb = &lds[(ph & 1) * (PPS * LBUF) + hloc * LSTR + wloc];

        float2 a0[GPC], a1[GPC];
#pragma unroll
        for (int c = 0; c < GPC; ++c) {
            a0[c] = make_float2(0.f, 0.f);
            a1[c] = make_float2(0.f, 0.f);
        }

#pragma unroll
        for (int t = 0; t < NTAP; ++t) {
            const int i = t / CK, j = t % CK;
            float2 f[PPS];
#pragma unroll
            for (int p = 0; p < PPS; ++p)
                f[p] = lb[p * LBUF + i * LSTR + j];   // ds_read_b64: ch 2p,2p+1

#pragma unroll
            for (int p = 0; p < PPS; ++p) {
                a0[2 * p].x     += m0[t].x * f[p].x;  a0[2 * p].y     += m0[t].y * f[p].x;
                a1[2 * p].x     += m1[t].x * f[p].x;  a1[2 * p].y     += m1[t].y * f[p].x;
                a0[2 * p + 1].x += m0[t].x * f[p].y;  a0[2 * p + 1].y += m0[t].y * f[p].y;
                a1[2 * p + 1].x += m1[t].x * f[p].y;  a1[2 * p + 1].y += m1[t].y * f[p].y;
            }
        }

        // ---- coalesced plain stores: 128 B contiguous per 16 lanes ----
        float* opb = obase + (size_t)(ph * GPC) * (OH * OW);
#pragma unroll
        for (int c = 0; c < GPC; ++c) {
            float* op = opb + (size_t)c * (OH * OW);
            *(f32x2*)op        = (f32x2){a0[c].x, a0[c].y};
            *(f32x2*)(op + OW) = (f32x2){a1[c].x, a1[c].y};
        }
    }
}

extern "C" void kernel_launch(void* const* d_in, const int* in_sizes, int n_in,
                              void* d_out, int out_size, void* d_ws, size_t ws_size,
                              hipStream_t stream) {
    const float* feat  = (const float*)d_in[0];
    const float* masks = (const float*)d_in[1];
    float* out = (float*)d_out;

    dim3 grid(CW / TILE, CH / TILE, CN * (CC / CPB));  // 4 x 4 x 32 = 512 blocks
    dim3 block(256);
    hipLaunchKernelGGL(carafe_kernel, grid, block, 0, stream, feat, masks, out);
}